// Round 10
// baseline (12.590 us; speedup 1.0000x reference)
//
#include <hip/hip_runtime.h>
#include <hip/hip_bf16.h>
#include <stdint.h>

#define NPTS 8192
#define DIM  64
#define NB   4
#define KK   9
#define BQ   64       // queries per block
#define RROWS 160     // staged rows: m = n0-90+r (row 0 = pad so gbase is EVEN)
#define SD2  72       // stage row stride in bf16 elems (144 B, 16B-aligned)
#define UD3  100      // key stride per query (uints): 96 t-major slots + pad (mod 32 = 4)

typedef short bf16x8 __attribute__((ext_vector_type(8)));
typedef float f32x4  __attribute__((ext_vector_type(4)));

static __device__ __forceinline__ uint32_t umin32(uint32_t a, uint32_t b) {
    return a < b ? a : b;
}

// DPP lane-xor within 8-lane groups (pure VALU, no LDS pipe):
// xor1 = quad_perm[1,0,3,2] (0xB1), xor2 = quad_perm[2,3,0,1] (0x4E),
// xor7 = row_half_mirror (0x141). After xor1+xor2 each quad holds its quad-min;
// partner s^7 is in the other quad, so min(self, s^7) = min of all 8 lanes.
#define DPP_MIN(mn, ctrl)                                                         \
    mn = umin32((uint32_t)__builtin_amdgcn_update_dpp((int)(mn), (int)(mn),       \
                                                      (ctrl), 0xF, 0xF, false),  \
                (mn))

// 3-barrier fused KNN (R9 = 12.53us), keys stored t-major for b128 select reads:
//   key (q, wofs) lives at ud[q*100 + (wofs&7)*12 + (wofs>>3)], so lane s's 12
//   candidates (wofs = s+8t) are 12 contiguous uints -> 3x ds_read_b128.
//   stage bf16 (float2 pair loads, clamped unmasked) + psum -> bar1 ->
//   A-frag prefetch || psum reduce -> bar2 ->
//   banded MFMA (nrt split, setprio 1) + key pack (t-major addr) -> bar3 ->
//   8-lane/query top-9 extraction (tree-min + DPP reduce).
// Row r <-> point m = n0-90+r. Query q (n = n0+q) = row q+90.
// Window candidate m = n-89+wofs = row q+1+wofs, wofs in [0,89]; rel = r-q-1.
// Unwritten t-major slots (wofs>89) are garbage but masked to MAX in selection.
__global__ __launch_bounds__(512, 4) void knn_fused(const float* __restrict__ x,
                                                    int* __restrict__ out) {
    __shared__ uint32_t ud[BQ * UD3];      // 25600 B keys; head doubles as psum
    __shared__ ushort   sb[RROWS * SD2];   // 23040 B staged bf16 rows
    __shared__ float    rnArr[RROWS];      // 640 B inverse norms

    float2* psumA = (float2*)ud;           // [512] row-pair partials (region 1)
    float2* psumB = (float2*)ud + 512;     // [128] = 8 waves x 16 row-pair partials (reg 2)

    const int tid = threadIdx.x;
    // XCD-chunked swizzle: same-XCD blocks take consecutive tiles -> window L2 hits
    const int blk = blockIdx.x;
    const int L   = (blk & 7) * 64 + (blk >> 3);   // bijective on 512 blocks
    const int b   = L >> 7;                        // 128 tiles per batch
    const int n0  = (L & 127) << 6;
    const int gbase = n0 - 90;                     // EVEN

    const float* xb = x + (size_t)b * DIM * NPTS;

    const int w = tid >> 6;
    const int l = tid & 63;

    // ---- stage region 1: rows 0..127 as 64 lane-pairs; wave w covers d in [8w,8w+7] ----
    // Each float2 load: 64 lanes x 8 B consecutive n -> 512 B contiguous segment.
    {
        const int g2 = l * 2;                      // row pair (g2, g2+1)
        const int gg = gbase + g2;
        const int gs = (gg < 0) ? 0 : gg;          // clamp only; no value masking
        const float* src = xb + gs;
        float s0 = 0.f, s1 = 0.f;
        uint32_t pkA[4], pkB[4];
#pragma unroll
        for (int e = 0; e < 4; ++e) {
            const int d = 8 * w + 2 * e;
            float2 v = *reinterpret_cast<const float2*>(&src[(size_t)d * NPTS]);
            float2 u = *reinterpret_cast<const float2*>(&src[(size_t)(d + 1) * NPTS]);
            s0 += v.x * v.x + u.x * u.x;
            s1 += v.y * v.y + u.y * u.y;
            __hip_bfloat162 hA = __float22bfloat162_rn(make_float2(v.x, u.x));
            __hip_bfloat162 hB = __float22bfloat162_rn(make_float2(v.y, u.y));
            pkA[e] = *reinterpret_cast<uint32_t*>(&hA);
            pkB[e] = *reinterpret_cast<uint32_t*>(&hB);
        }
        *reinterpret_cast<uint4*>(&sb[(size_t)g2 * SD2 + 8 * w]) =
            make_uint4(pkA[0], pkA[1], pkA[2], pkA[3]);
        *reinterpret_cast<uint4*>(&sb[(size_t)(g2 + 1) * SD2 + 8 * w]) =
            make_uint4(pkB[0], pkB[1], pkB[2], pkB[3]);
        psumA[tid] = make_float2(s0, s1);
    }
    // ---- stage region 2: rows 128..159 as 16 lane-pairs x 32 d-pairs ----
    {
        const int g2 = 128 + (l & 15) * 2;
        const int c  = (w << 2) | (l >> 4);        // 0..31: d pair (2c, 2c+1)
        const int gg = gbase + g2;                 // >= 38 always
        const int gs = (gg > NPTS - 2) ? (NPTS - 2) : gg;
        const float* src = xb + gs;
        float2 v = *reinterpret_cast<const float2*>(&src[(size_t)(2 * c) * NPTS]);
        float2 u = *reinterpret_cast<const float2*>(&src[(size_t)(2 * c + 1) * NPTS]);
        float s0 = v.x * v.x + u.x * u.x;
        float s1 = v.y * v.y + u.y * u.y;
        __hip_bfloat162 hA = __float22bfloat162_rn(make_float2(v.x, u.x));
        __hip_bfloat162 hB = __float22bfloat162_rn(make_float2(v.y, u.y));
        *reinterpret_cast<uint32_t*>(&sb[(size_t)g2 * SD2 + 2 * c]) =
            *reinterpret_cast<uint32_t*>(&hA);
        *reinterpret_cast<uint32_t*>(&sb[(size_t)(g2 + 1) * SD2 + 2 * c]) =
            *reinterpret_cast<uint32_t*>(&hB);
        // in-wave pre-reduce over the 4 c-values sharing this row pair (lanes l, l^16, l^32)
        s0 += __shfl_xor(s0, 16); s0 += __shfl_xor(s0, 32);
        s1 += __shfl_xor(s1, 16); s1 += __shfl_xor(s1, 32);
        if (l < 16) psumB[w * 16 + l] = make_float2(s0, s1);
    }
    __syncthreads();   // bar1: sb + psum visible

    // ---- A-frag prefetch (sb valid) overlapped with inverse-norm reduce ----
    const int qt = w >> 1;            // query tile 0..3
    const int h  = w & 1;             // row-tile half
    const int lr = l & 15;
    const int lk = l >> 4;
    const int nrt = 4 - h;            // 4 or 3 row tiles (band rows 16qt .. 16qt+111)

    const ushort* ap = &sb[(size_t)(90 + qt * 16 + lr) * SD2 + lk * 8];
    bf16x8 a0 = *reinterpret_cast<const bf16x8*>(ap);
    bf16x8 a1 = *reinterpret_cast<const bf16x8*>(ap + 32);

    if (tid < 128) {
        const int gp = tid >> 1, comp = tid & 1;
        float s = 0.f;
#pragma unroll
        for (int k = 0; k < 8; ++k)
            s += reinterpret_cast<const float*>(&psumA[k * 64 + gp])[comp];
        rnArr[tid] = 1.0f / fmaxf(sqrtf(s), 1e-12f);
    } else if (tid < 160) {
        const int rr = tid - 128;
        const int gp = rr >> 1, comp = rr & 1;
        float s = 0.f;
#pragma unroll
        for (int k = 0; k < 8; ++k)
            s += reinterpret_cast<const float*>(&psumB[k * 16 + gp])[comp];
        rnArr[tid] = 1.0f / fmaxf(sqrtf(s), 1e-12f);
    }
    __syncthreads();   // bar2: rnArr visible; psum dead (ud writes now safe)

    // ---- banded MFMA (nrt split) + t-major key pack ----
    {
        float rq[4];
#pragma unroll
        for (int j = 0; j < 4; ++j) rq[j] = rnArr[90 + qt * 16 + lk * 4 + j];
        const int q0 = qt * 16 + lk * 4;
        __builtin_amdgcn_s_setprio(1);     // favor MFMA-issuing wave vs other block's phases
#pragma unroll
        for (int i = 0; i < 4; ++i) {
            if (i < nrt) {
                const int rto = h * 4 + i;
                const int rbase = qt * 16 + rto * 16;
                const ushort* bp = &sb[(size_t)(rbase + lr) * SD2 + lk * 8];
                bf16x8 b0 = *reinterpret_cast<const bf16x8*>(bp);
                bf16x8 b1 = *reinterpret_cast<const bf16x8*>(bp + 32);
                f32x4 acc = {0.f, 0.f, 0.f, 0.f};
                acc = __builtin_amdgcn_mfma_f32_16x16x32_bf16(a0, b0, acc, 0, 0, 0);
                acc = __builtin_amdgcn_mfma_f32_16x16x32_bf16(a1, b1, acc, 0, 0, 0);
                const int r = rbase + lr;
                const float rnr = rnArr[r];
#pragma unroll
                for (int j = 0; j < 4; ++j) {
                    int rel = r - (q0 + j) - 1;      // window offset wofs
                    if (rel >= 0 && rel <= 89) {
                        float p = acc[j] * rq[j] * rnr;
                        float dist = 2.0f - 2.0f * p;
                        uint32_t uu = __float_as_uint(dist);
                        uu = (uu & 0x80000000u) ? ~uu : (uu | 0x80000000u);
                        const int pos = (rel & 7) * 12 + (rel >> 3);   // t-major slot
                        ud[(q0 + j) * UD3 + pos] = (uu & 0xFFFFFF80u) | (uint32_t)rel;
                    }
                }
            }
        }
        __builtin_amdgcn_s_setprio(0);
    }
    __syncthreads();   // bar3: keys visible

    // ---- selection: 8 lanes per query, 9 rounds of masked-min extraction ----
    {
        const int ql = l >> 3;             // 0..7
        const int s  = l & 7;              // 0..7
        const int q  = (w << 3) | ql;      // 0..63
        const int n  = n0 + q;

        // lane s's 12 candidates are contiguous: ud[q*100 + s*12 .. +11]
        const uint32_t* urow = &ud[q * UD3 + s * 12];
        uint4 k0 = *reinterpret_cast<const uint4*>(urow);
        uint4 k1 = *reinterpret_cast<const uint4*>(urow + 4);
        uint4 k2 = *reinterpret_cast<const uint4*>(urow + 8);
        uint32_t key[12] = {k0.x, k0.y, k0.z, k0.w,
                            k1.x, k1.y, k1.z, k1.w,
                            k2.x, k2.y, k2.z, k2.w};
#pragma unroll
        for (int t = 0; t < 12; ++t) {
            int wofs = s + 8 * t;          // window offset 0..95
            int m = n - 89 + wofs;
            bool ok = (wofs <= 89) && (m >= 0);
            key[t] = ok ? key[t] : 0xFFFFFFFFu;
        }

        uint32_t prev = 0;
        int omKeep = n;
        int om8 = n;
#pragma unroll
        for (int j = 0; j < KK; ++j) {
            uint32_t cc[12];
#pragma unroll
            for (int t = 0; t < 12; ++t)
                cc[t] = (key[t] > prev) ? key[t] : 0xFFFFFFFFu;
            // depth-4 tree (v_min3-friendly): bit-identical to sequential min
            uint32_t g0 = umin32(umin32(cc[0], cc[1]), cc[2]);
            uint32_t g1 = umin32(umin32(cc[3], cc[4]), cc[5]);
            uint32_t g2 = umin32(umin32(cc[6], cc[7]), cc[8]);
            uint32_t g3 = umin32(umin32(cc[9], cc[10]), cc[11]);
            uint32_t mn = umin32(umin32(g0, g1), umin32(g2, g3));
            // 8-lane min reduce on the VALU pipe (DPP), no LDS traffic
            DPP_MIN(mn, 0xB1);             // quad_perm [1,0,3,2]  (xor 1)
            DPP_MIN(mn, 0x4E);             // quad_perm [2,3,0,1]  (xor 2)
            DPP_MIN(mn, 0x141);            // row_half_mirror      (xor 7)
            int om = (mn == 0xFFFFFFFFu) ? n : (n - 89 + (int)(mn & 127u));
            if (j < 8) {
                if (s == j) omKeep = om;
            } else {
                om8 = om;
            }
            prev = mn;
        }

        const int base0 = (b * NPTS + n) * KK;
        const int base1 = NB * NPTS * KK + base0;
        out[base0 + s] = omKeep;           // 8 coalesced lanes per query
        out[base1 + s] = n;
        if (s == 0) {
            out[base0 + 8] = om8;
            out[base1 + 8] = n;
        }
    }
}

extern "C" void kernel_launch(void* const* d_in, const int* in_sizes, int n_in,
                              void* d_out, int out_size, void* d_ws, size_t ws_size,
                              hipStream_t stream) {
    const float* x = (const float*)d_in[0];
    int* out = (int*)d_out;
    knn_fused<<<NB * (NPTS / BQ), 512, 0, stream>>>(x, out);
}

// Round 11
// 12.535 us; speedup vs baseline: 1.0044x; 1.0044x over previous
//
#include <hip/hip_runtime.h>
#include <hip/hip_bf16.h>
#include <stdint.h>

#define NPTS 8192
#define DIM  64
#define NB   4
#define KK   9
#define BQ   64       // queries per block
#define RROWS 160     // staged rows: m = n0-90+r (row 0 = pad so gbase is EVEN)
#define SD2  72       // stage row stride in bf16 elems (144 B, 16B-aligned)
#define UD2  91       // key stride per query (uints): wofs 0..89 + pad

typedef short bf16x8 __attribute__((ext_vector_type(8)));
typedef float f32x4  __attribute__((ext_vector_type(4)));

static __device__ __forceinline__ uint32_t umin32(uint32_t a, uint32_t b) {
    return a < b ? a : b;
}

// DPP lane-xor within 8-lane groups (pure VALU, no LDS pipe):
// xor1 = quad_perm[1,0,3,2] (0xB1), xor2 = quad_perm[2,3,0,1] (0x4E),
// xor7 = row_half_mirror (0x141). After xor1+xor2 each quad holds its quad-min;
// partner s^7 is in the other quad, so min(self, s^7) = min of all 8 lanes
// (bit-identical to the shfl_xor 1/2/4 reduction: same 8 distinct values).
#define DPP_MIN(mn, ctrl)                                                         \
    mn = umin32((uint32_t)__builtin_amdgcn_update_dpp((int)(mn), (int)(mn),       \
                                                      (ctrl), 0xF, 0xF, false),  \
                (mn))

// R9 structure = session best (12.53us). 3-barrier fused KNN:
//   stage bf16 (float2 pair loads, clamped unmasked) + psum -> bar1 ->
//   A-frag prefetch || psum reduce -> bar2 ->
//   banded MFMA (nrt split, setprio 1) + key pack -> bar3 ->
//   8-lane/query top-9 extraction (tree-min + DPP reduce).
// Row r <-> point m = n0-90+r. Query q (n = n0+q) = row q+90.
// Window candidate m = n-89+wofs = row q+1+wofs, wofs in [0,89]; rel = r-q-1.
// Garbage-safety: rows with m<0 or m>=NPTS are staged unmasked (clamped addr);
// their keys are either never packed (rel out of [0,89]) or masked to MAX in
// selection (m<0 check) - so no load masking is needed anywhere.
__global__ __launch_bounds__(512, 4) void knn_fused(const float* __restrict__ x,
                                                    int* __restrict__ out) {
    __shared__ uint32_t ud[BQ * UD2];      // 23296 B keys [q][wofs]; head doubles as psum
    __shared__ ushort   sb[RROWS * SD2];   // 23040 B staged bf16 rows
    __shared__ float    rnArr[RROWS];      // 640 B inverse norms

    float2* psumA = (float2*)ud;           // [512] row-pair partials (region 1)
    float2* psumB = (float2*)ud + 512;     // [128] = 8 waves x 16 row-pair partials (reg 2)

    const int tid = threadIdx.x;
    // XCD-chunked swizzle: same-XCD blocks take consecutive tiles -> window L2 hits
    const int blk = blockIdx.x;
    const int L   = (blk & 7) * 64 + (blk >> 3);   // bijective on 512 blocks
    const int b   = L >> 7;                        // 128 tiles per batch
    const int n0  = (L & 127) << 6;
    const int gbase = n0 - 90;                     // EVEN

    const float* xb = x + (size_t)b * DIM * NPTS;

    const int w = tid >> 6;
    const int l = tid & 63;

    // ---- stage region 1: rows 0..127 as 64 lane-pairs; wave w covers d in [8w,8w+7] ----
    // Each float2 load: 64 lanes x 8 B consecutive n -> 512 B contiguous segment.
    {
        const int g2 = l * 2;                      // row pair (g2, g2+1)
        const int gg = gbase + g2;
        const int gs = (gg < 0) ? 0 : gg;          // clamp only; no value masking
        const float* src = xb + gs;
        float s0 = 0.f, s1 = 0.f;
        uint32_t pkA[4], pkB[4];
#pragma unroll
        for (int e = 0; e < 4; ++e) {
            const int d = 8 * w + 2 * e;
            float2 v = *reinterpret_cast<const float2*>(&src[(size_t)d * NPTS]);
            float2 u = *reinterpret_cast<const float2*>(&src[(size_t)(d + 1) * NPTS]);
            s0 += v.x * v.x + u.x * u.x;
            s1 += v.y * v.y + u.y * u.y;
            __hip_bfloat162 hA = __float22bfloat162_rn(make_float2(v.x, u.x));
            __hip_bfloat162 hB = __float22bfloat162_rn(make_float2(v.y, u.y));
            pkA[e] = *reinterpret_cast<uint32_t*>(&hA);
            pkB[e] = *reinterpret_cast<uint32_t*>(&hB);
        }
        *reinterpret_cast<uint4*>(&sb[(size_t)g2 * SD2 + 8 * w]) =
            make_uint4(pkA[0], pkA[1], pkA[2], pkA[3]);
        *reinterpret_cast<uint4*>(&sb[(size_t)(g2 + 1) * SD2 + 8 * w]) =
            make_uint4(pkB[0], pkB[1], pkB[2], pkB[3]);
        psumA[tid] = make_float2(s0, s1);
    }
    // ---- stage region 2: rows 128..159 as 16 lane-pairs x 32 d-pairs ----
    {
        const int g2 = 128 + (l & 15) * 2;
        const int c  = (w << 2) | (l >> 4);        // 0..31: d pair (2c, 2c+1)
        const int gg = gbase + g2;                 // >= 38 always
        const int gs = (gg > NPTS - 2) ? (NPTS - 2) : gg;
        const float* src = xb + gs;
        float2 v = *reinterpret_cast<const float2*>(&src[(size_t)(2 * c) * NPTS]);
        float2 u = *reinterpret_cast<const float2*>(&src[(size_t)(2 * c + 1) * NPTS]);
        float s0 = v.x * v.x + u.x * u.x;
        float s1 = v.y * v.y + u.y * u.y;
        __hip_bfloat162 hA = __float22bfloat162_rn(make_float2(v.x, u.x));
        __hip_bfloat162 hB = __float22bfloat162_rn(make_float2(v.y, u.y));
        *reinterpret_cast<uint32_t*>(&sb[(size_t)g2 * SD2 + 2 * c]) =
            *reinterpret_cast<uint32_t*>(&hA);
        *reinterpret_cast<uint32_t*>(&sb[(size_t)(g2 + 1) * SD2 + 2 * c]) =
            *reinterpret_cast<uint32_t*>(&hB);
        // in-wave pre-reduce over the 4 c-values sharing this row pair (lanes l, l^16, l^32)
        s0 += __shfl_xor(s0, 16); s0 += __shfl_xor(s0, 32);
        s1 += __shfl_xor(s1, 16); s1 += __shfl_xor(s1, 32);
        if (l < 16) psumB[w * 16 + l] = make_float2(s0, s1);
    }
    __syncthreads();   // bar1: sb + psum visible

    // ---- A-frag prefetch (sb valid) overlapped with inverse-norm reduce ----
    const int qt = w >> 1;            // query tile 0..3
    const int h  = w & 1;             // row-tile half
    const int lr = l & 15;
    const int lk = l >> 4;
    const int nrt = 4 - h;            // 4 or 3 row tiles (band rows 16qt .. 16qt+111)

    const ushort* ap = &sb[(size_t)(90 + qt * 16 + lr) * SD2 + lk * 8];
    bf16x8 a0 = *reinterpret_cast<const bf16x8*>(ap);
    bf16x8 a1 = *reinterpret_cast<const bf16x8*>(ap + 32);

    if (tid < 128) {
        const int gp = tid >> 1, comp = tid & 1;
        float s = 0.f;
#pragma unroll
        for (int k = 0; k < 8; ++k)
            s += reinterpret_cast<const float*>(&psumA[k * 64 + gp])[comp];
        rnArr[tid] = 1.0f / fmaxf(sqrtf(s), 1e-12f);
    } else if (tid < 160) {
        const int rr = tid - 128;
        const int gp = rr >> 1, comp = rr & 1;
        float s = 0.f;
#pragma unroll
        for (int k = 0; k < 8; ++k)
            s += reinterpret_cast<const float*>(&psumB[k * 16 + gp])[comp];
        rnArr[tid] = 1.0f / fmaxf(sqrtf(s), 1e-12f);
    }
    __syncthreads();   // bar2: rnArr visible; psum dead (ud writes now safe)

    // ---- banded MFMA (nrt split) + compact key pack ----
    {
        float rq[4];
#pragma unroll
        for (int j = 0; j < 4; ++j) rq[j] = rnArr[90 + qt * 16 + lk * 4 + j];
        const int q0 = qt * 16 + lk * 4;
        __builtin_amdgcn_s_setprio(1);     // favor MFMA-issuing wave vs other block's phases
#pragma unroll
        for (int i = 0; i < 4; ++i) {
            if (i < nrt) {
                const int rto = h * 4 + i;
                const int rbase = qt * 16 + rto * 16;
                const ushort* bp = &sb[(size_t)(rbase + lr) * SD2 + lk * 8];
                bf16x8 b0 = *reinterpret_cast<const bf16x8*>(bp);
                bf16x8 b1 = *reinterpret_cast<const bf16x8*>(bp + 32);
                f32x4 acc = {0.f, 0.f, 0.f, 0.f};
                acc = __builtin_amdgcn_mfma_f32_16x16x32_bf16(a0, b0, acc, 0, 0, 0);
                acc = __builtin_amdgcn_mfma_f32_16x16x32_bf16(a1, b1, acc, 0, 0, 0);
                const int r = rbase + lr;
                const float rnr = rnArr[r];
#pragma unroll
                for (int j = 0; j < 4; ++j) {
                    int rel = r - (q0 + j) - 1;      // window offset wofs
                    if (rel >= 0 && rel <= 89) {
                        float p = acc[j] * rq[j] * rnr;
                        float dist = 2.0f - 2.0f * p;
                        uint32_t uu = __float_as_uint(dist);
                        uu = (uu & 0x80000000u) ? ~uu : (uu | 0x80000000u);
                        ud[(q0 + j) * UD2 + rel] = (uu & 0xFFFFFF80u) | (uint32_t)rel;
                    }
                }
            }
        }
        __builtin_amdgcn_s_setprio(0);
    }
    __syncthreads();   // bar3: keys visible

    // ---- selection: 8 lanes per query, 9 rounds of masked-min extraction ----
    {
        const int ql = l >> 3;             // 0..7
        const int s  = l & 7;              // 0..7
        const int q  = (w << 3) | ql;      // 0..63
        const int n  = n0 + q;

        uint32_t key[12];
#pragma unroll
        for (int t = 0; t < 12; ++t) {
            int wofs = s + 8 * t;          // window offset 0..95
            int m = n - 89 + wofs;
            bool ok = (wofs <= 89) && (m >= 0);
            uint32_t raw = ud[q * UD2 + (ok ? wofs : 0)];
            key[t] = ok ? raw : 0xFFFFFFFFu;
        }

        uint32_t prev = 0;
        int omKeep = n;
        int om8 = n;
#pragma unroll
        for (int j = 0; j < KK; ++j) {
            uint32_t cc[12];
#pragma unroll
            for (int t = 0; t < 12; ++t)
                cc[t] = (key[t] > prev) ? key[t] : 0xFFFFFFFFu;
            // depth-4 tree (v_min3-friendly): bit-identical to sequential min
            uint32_t g0 = umin32(umin32(cc[0], cc[1]), cc[2]);
            uint32_t g1 = umin32(umin32(cc[3], cc[4]), cc[5]);
            uint32_t g2 = umin32(umin32(cc[6], cc[7]), cc[8]);
            uint32_t g3 = umin32(umin32(cc[9], cc[10]), cc[11]);
            uint32_t mn = umin32(umin32(g0, g1), umin32(g2, g3));
            // 8-lane min reduce on the VALU pipe (DPP), no LDS traffic
            DPP_MIN(mn, 0xB1);             // quad_perm [1,0,3,2]  (xor 1)
            DPP_MIN(mn, 0x4E);             // quad_perm [2,3,0,1]  (xor 2)
            DPP_MIN(mn, 0x141);            // row_half_mirror      (xor 7)
            int om = (mn == 0xFFFFFFFFu) ? n : (n - 89 + (int)(mn & 127u));
            if (j < 8) {
                if (s == j) omKeep = om;
            } else {
                om8 = om;
            }
            prev = mn;
        }

        const int base0 = (b * NPTS + n) * KK;
        const int base1 = NB * NPTS * KK + base0;
        out[base0 + s] = omKeep;           // 8 coalesced lanes per query
        out[base1 + s] = n;
        if (s == 0) {
            out[base0 + 8] = om8;
            out[base1 + 8] = n;
        }
    }
}

extern "C" void kernel_launch(void* const* d_in, const int* in_sizes, int n_in,
                              void* d_out, int out_size, void* d_ws, size_t ws_size,
                              hipStream_t stream) {
    const float* x = (const float*)d_in[0];
    int* out = (int*)d_out;
    knn_fused<<<NB * (NPTS / BQ), 512, 0, stream>>>(x, out);
}